// Round 5
// baseline (12775.146 us; speedup 1.0000x reference)
//
#include <hip/hip_runtime.h>
#include <math.h>

// ---------------------------------------------------------------------------
// TimeSeriesTransformerDecoder — cooperative mega-kernel, v5.
//  * KV-cached incremental decoding (exact). Cross-attn T=1 -> const ca_add.
//  * v5 vs v4: (1) all bulk stores = global_store_dwordx4 sc0 sc1 (v4's
//    scalar sc1 stores had ~16x write amplification: WRITE_SIZE 4.37GB);
//    (2) launch-invariant buffers (kcache/vcache/ca_add/memory/pe/vals) read
//    via PLAIN cached loads (write-once-per-launch => L2-safe; proven by
//    harness memcpy-restore + v3 plain weight reads); (3) XCD-swizzled job
//    maps so the 4 m-jobs sharing a W-tile hit the same XCD L2.
// ---------------------------------------------------------------------------

#define B    256
#define D    512
#define H    8
#define HD   64
#define L    4
#define FF   2048
#define P    24
#define NBLK 256
#define NTHR 512
#define NGRP 8
#define GSZ  32
#define CS   ((size_t)B * H * P * HD)   // per-layer KV-cache stride

typedef float f4 __attribute__((ext_vector_type(4)));
typedef float f2 __attribute__((ext_vector_type(2)));

struct MegaArgs {
  const float *context, *start_token, *ctx_W, *ctx_b, *ve_W, *ve_b;
  const float *sa_in_w, *sa_in_b, *sa_out_w, *sa_out_b;
  const float *ca_in_w, *ca_in_b, *ca_out_w, *ca_out_b;
  const float *lin1_w, *lin1_b, *lin2_w, *lin2_b;
  const float *ln1_w, *ln1_b, *ln2_w, *ln2_b, *ln3_w, *ln3_b;
  const float *o1_w, *o1_b, *o2_w, *o2_b;
  float *out;
  float *pe, *vals, *memory, *ca_add, *x, *qbuf, *hbuf, *part, *hh,
        *kcache, *vcache;
};

// ---- coherent scalar access (relaxed agent atomics: sc0 sc1, no flush)
__device__ __forceinline__ float gld(const float* p)
{
  return __hip_atomic_load((float*)p, __ATOMIC_RELAXED,
                           __HIP_MEMORY_SCOPE_AGENT);
}
__device__ __forceinline__ void gst(float* p, float v)
{
  __hip_atomic_store(p, v, __ATOMIC_RELAXED, __HIP_MEMORY_SCOPE_AGENT);
}
// ---- coherent vector stores / loads (inline asm, dwordx4 sc0 sc1)
__device__ __forceinline__ void gst4(float* p, f4 v)
{
  asm volatile("global_store_dwordx4 %0, %1, off sc0 sc1"
               :: "v"(p), "v"(v) : "memory");
}
__device__ __forceinline__ f4 gld4e(const float* p)   // embedded wait
{
  f4 r;
  asm volatile("global_load_dwordx4 %0, %1, off sc0 sc1\n\t"
               "s_waitcnt vmcnt(0)"
               : "=&v"(r) : "v"(p) : "memory");
  return r;
}

// ---- barrier state: monotonic across graph replays, no resets.
__device__ __align__(128) unsigned g_cnt[NGRP * 32];
__device__ __align__(128) unsigned g_root = 0;
__device__ __align__(128) unsigned g_gen  = 0;
__device__ __align__(128) unsigned g_base = 0;

__device__ __forceinline__ void grid_bar(unsigned &bno)
{
  ++bno;
  // drain asm stores (invisible to compiler) before signaling arrival
  asm volatile("s_waitcnt vmcnt(0)" ::: "memory");
  __syncthreads();
  if (threadIdx.x == 0) {
    unsigned* cnt = &g_cnt[(blockIdx.x & (NGRP - 1)) * 32];
    const unsigned o = __hip_atomic_fetch_add(cnt, 1u, __ATOMIC_RELAXED,
                                              __HIP_MEMORY_SCOPE_AGENT);
    if (o == bno * GSZ - 1u) {
      const unsigned r = __hip_atomic_fetch_add(&g_root, 1u, __ATOMIC_RELAXED,
                                                __HIP_MEMORY_SCOPE_AGENT);
      if (r == bno * NGRP - 1u)
        __hip_atomic_store(&g_gen, bno, __ATOMIC_RELAXED,
                           __HIP_MEMORY_SCOPE_AGENT);
    }
    while (__hip_atomic_load(&g_gen, __ATOMIC_RELAXED,
                             __HIP_MEMORY_SCOPE_AGENT) < bno)
      __builtin_amdgcn_s_sleep(2);
  }
  __syncthreads();
}

__device__ __forceinline__ float gelu_f(float v)
{
  return 0.5f * v * (1.0f + erff(v * 0.70710678118654752f));
}
__device__ __forceinline__ f4 gelu4(f4 v)
{
  v.x = gelu_f(v.x); v.y = gelu_f(v.y); v.z = gelu_f(v.z); v.w = gelu_f(v.w);
  return v;
}

// ---------------------------------------------------------------------------
// 64x64 tile GEMM over K chunk [k0,k0+KL). 512 thr, 2x4 micro-tile.
// LOADER: 0 = sc1 gld(A); 1 = embedding on the fly; 2 = plain cached A.
// EPI: 0 = +bias; 1 = +bias+gelu; 2 = +bias, n<D->qbuf else kv caches;
//      3 = raw partial. All outputs via gst4.
// ---------------------------------------------------------------------------
template <int LOADER, int EPI>
__device__ void gemmK(float* sh,
                      const float* A, int lda,
                      const float* W, int ldw, const float* bias,
                      float* C, int ldc, int m0, int n0, int k0, int KL,
                      float* kcp, float* vcp, int t,
                      const float* valst, const float* veW, const float* veb,
                      const float* pet)
{
  float* As = sh;             // [16][68]
  float* Ws = sh + 16 * 68;
  const int tid = threadIdx.x;
  const int tm = tid >> 4;    // 0..31 -> rows tm*2, tm*2+1
  const int tn = tid & 15;    // 0..15 -> cols tn*4..+3
  float acc[2][4] = {};

  float vv0 = 0.f, vv1 = 0.f;
  if constexpr (LOADER == 1) {
    vv0 = valst[m0 + (tid >> 4)];          // plain: vals launch-invariant
    vv1 = valst[m0 + 32 + (tid >> 4)];
  }

  for (int kb = 0; kb < KL; kb += 16) {
#pragma unroll
    for (int i = 0; i < 2; i++) {
      const int idx = tid + i * 512;
      const int r = idx >> 4;              // 0..63
      const int c = idx & 15;
      const int k = k0 + kb + c;
      float av;
      if constexpr (LOADER == 1) {
        av = (i ? vv1 : vv0) * veW[k] + veb[k] + pet[k];
      } else if constexpr (LOADER == 2) {
        av = A[(size_t)(m0 + r) * lda + k];
      } else {
        av = gld(A + (size_t)(m0 + r) * lda + k);
      }
      As[c * 68 + r] = av;
      Ws[c * 68 + r] = W[(size_t)(n0 + r) * ldw + k];
    }
    __syncthreads();
#pragma unroll
    for (int kk = 0; kk < 16; kk++) {
      const f2 a2 = *(const f2*)(As + kk * 68 + tm * 2);
      const f4 w4 = *(const f4*)(Ws + kk * 68 + tn * 4);
      acc[0][0] = fmaf(a2.x, w4.x, acc[0][0]);
      acc[0][1] = fmaf(a2.x, w4.y, acc[0][1]);
      acc[0][2] = fmaf(a2.x, w4.z, acc[0][2]);
      acc[0][3] = fmaf(a2.x, w4.w, acc[0][3]);
      acc[1][0] = fmaf(a2.y, w4.x, acc[1][0]);
      acc[1][1] = fmaf(a2.y, w4.y, acc[1][1]);
      acc[1][2] = fmaf(a2.y, w4.z, acc[1][2]);
      acc[1][3] = fmaf(a2.y, w4.w, acc[1][3]);
    }
    __syncthreads();
  }

  const int n4 = n0 + tn * 4;
#pragma unroll
  for (int i = 0; i < 2; i++) {
    const int m = m0 + tm * 2 + i;
    f4 v;
    v.x = acc[i][0]; v.y = acc[i][1]; v.z = acc[i][2]; v.w = acc[i][3];
    if constexpr (EPI != 3) v += *(const f4*)(bias + n4);
    if constexpr (EPI == 1) v = gelu4(v);
    if constexpr (EPI == 2) {
      if (n4 < D) {
        gst4(C + (size_t)m * D + n4, v);                        // q
      } else if (n4 < 2 * D) {
        const int f = n4 - D;
        gst4(kcp + ((size_t)(m * H + (f >> 6)) * P + t) * HD + (f & 63), v);
      } else {
        const int f = n4 - 2 * D;
        gst4(vcp + ((size_t)(m * H + (f >> 6)) * P + t) * HD + (f & 63), v);
      }
    } else {
      gst4(C + (size_t)m * ldc + n4, v);
    }
  }
}

// row-sum over 128 threads (2 waves); block has 4 rows (512 threads)
__device__ __forceinline__ float rsum128(float v, float* sb)
{
#pragma unroll
  for (int o = 32; o; o >>= 1) v += __shfl_xor(v, o);
  const int w = threadIdx.x >> 6;
  if ((threadIdx.x & 63) == 0) sb[w] = v;
  __syncthreads();
  const int rl = threadIdx.x >> 7;
  const float s = sb[rl * 2] + sb[rl * 2 + 1];
  __syncthreads();
  return s;
}

// XCD-swizzled job maps: same-W-tile m-jobs land on same (blk&7) => same XCD
#define NKMAP(b) ((((b) >> 5) << 3) | ((b) & 7))
#define MMAP(b)  (((b) >> 3) & 3)

__global__ __launch_bounds__(NTHR) void mega(MegaArgs a)
{
  __shared__ float sh[2 * 16 * 68];
  __shared__ float sbf[8];
  const int blk = blockIdx.x;
  unsigned bno = __hip_atomic_load(&g_base, __ATOMIC_RELAXED,
                                   __HIP_MEMORY_SCOPE_AGENT);
  float* attn_o = a.part + (size_t)4 * B * D;   // alias: part[4] slot

  // ---- S1: memory = context @ ctx_W^T + b | pe table | vals init
  if (blk < 32) {
    gemmK<2, 0>(sh, a.context, 512, a.ctx_W, 512, a.ctx_b, a.memory, D,
                (blk & 3) * 64, (blk >> 2) * 64, 0, 512,
                nullptr, nullptr, 0, nullptr, nullptr, nullptr, nullptr);
  } else if (blk < 56) {
    const int tt = blk - 32;
    const int dd = threadIdx.x;
    const float fr = expf((float)(dd & ~1) * (-9.210340371976184f / (float)D));
    const float ang = (float)tt * fr;
    gst(a.pe + tt * D + dd, (dd & 1) ? cosf(ang) : sinf(ang));
  } else if (blk == 56) {
    if (threadIdx.x < B) gst(a.vals + threadIdx.x, a.start_token[0]);
  }
  grid_bar(bno);

  // ---- S2: part[l] = memory @ Wv_ca[l]^T + bv   (T=1 cross-attn value)
  if (blk < 128) {
    const int l = blk >> 5, tile = blk & 31;
    gemmK<2, 0>(sh, a.memory, D,
                a.ca_in_w + (size_t)l * 3 * D * D + (size_t)2 * D * D, D,
                a.ca_in_b + l * 3 * D + 2 * D,
                a.part + (size_t)l * B * D, D,
                (tile & 3) * 64, (tile >> 2) * 64, 0, 512,
                nullptr, nullptr, 0, nullptr, nullptr, nullptr, nullptr);
  }
  grid_bar(bno);

  // ---- S3: ca_add[l] = part[l] @ Wo_ca[l]^T + bo  (first read of part)
  if (blk < 128) {
    const int l = blk >> 5, tile = blk & 31;
    gemmK<2, 0>(sh, a.part + (size_t)l * B * D, D,
                a.ca_out_w + (size_t)l * D * D, D, a.ca_out_b + l * D,
                a.ca_add + (size_t)l * B * D, D,
                (tile & 3) * 64, (tile >> 2) * 64, 0, 512,
                nullptr, nullptr, 0, nullptr, nullptr, nullptr, nullptr);
  }
  grid_bar(bno);

  // ---- autoregressive decode --------------------------------------------
  for (int t = 0; t < P; t++) {
    for (int l = 0; l < L; l++) {
      float* kcp = a.kcache + (size_t)l * CS;
      float* vcp = a.vcache + (size_t)l * CS;

      // QKV projection (96 jobs, XCD-swizzled); l==0: embedding inline
      if (blk < 96) {
        const int m0 = MMAP(blk) * 64, n0 = NKMAP(blk) * 64;
        if (l == 0)
          gemmK<1, 2>(sh, nullptr, 0, a.sa_in_w, D, a.sa_in_b, a.qbuf, D,
                      m0, n0, 0, 512, kcp, vcp, t,
                      a.vals + (size_t)t * B, a.ve_W, a.ve_b,
                      a.pe + (size_t)t * D);
        else
          gemmK<0, 2>(sh, a.x, D, a.sa_in_w + (size_t)l * 3 * D * D, D,
                      a.sa_in_b + l * 3 * D, a.qbuf, D, m0, n0, 0, 512,
                      kcp, vcp, t, nullptr, nullptr, nullptr, nullptr);
      }
      grid_bar(bno);

      // causal attention: one wave per (b,h); K/V via PLAIN f4 (L2-cached)
      {
        const int wid = threadIdx.x >> 6, lane = threadIdx.x & 63;
        const int u = blk * 8 + wid;
        const int b = u >> 3, h = u & 7;
        const int g = lane >> 4;
        const int hd0 = (lane & 15) * 4;
        const float* kb = kcp + (size_t)(b * H + h) * P * HD;
        const float* vb = vcp + (size_t)(b * H + h) * P * HD;
        const f4 q4 = gld4e(a.qbuf + (size_t)b * D + h * HD + hd0);
        const int nn = t + 1;
        float p[6];
#pragma unroll
        for (int bt = 0; bt < 6; bt++) {
          const int j = bt * 4 + g;
          float s = -1e30f;
          if (j < nn) {
            const f4 k4 = *(const f4*)(kb + j * HD + hd0);
            s = q4.x * k4.x + q4.y * k4.y + q4.z * k4.z + q4.w * k4.w;
          }
#pragma unroll
          for (int o = 1; o <= 8; o <<= 1) s += __shfl_xor(s, o);
          p[bt] = s * 0.125f;                 // 1/sqrt(64)
        }
        float mx = -1e30f;
#pragma unroll
        for (int bt = 0; bt < 6; bt++)
          if (bt * 4 + g < nn) mx = fmaxf(mx, p[bt]);
        mx = fmaxf(mx, __shfl_xor(mx, 16));
        mx = fmaxf(mx, __shfl_xor(mx, 32));
        float sum = 0.f;
#pragma unroll
        for (int bt = 0; bt < 6; bt++) {
          const int j = bt * 4 + g;
          const float e = (j < nn) ? expf(p[bt] - mx) : 0.f;
          p[bt] = e; sum += e;
        }
        sum += __shfl_xor(sum, 16);
        sum += __shfl_xor(sum, 32);
        const float inv = 1.0f / sum;
        f4 o4 = {0.f, 0.f, 0.f, 0.f};
#pragma unroll
        for (int j = 0; j < P; j++)
          if (j < nn) {
            const float pj = __shfl(p[j >> 2], ((j & 3) << 4) | (lane & 15));
            const f4 v4 = *(const f4*)(vb + j * HD + hd0);
            o4 += (pj * inv) * v4;
          }
        gst4(attn_o + (size_t)b * D + h * HD + hd0, o4);
      }
      grid_bar(bno);

      // out-proj split-K4 (128 jobs, swizzled): part[kc] partials
      if (blk < 128) {
        const int nk = NKMAP(blk);
        gemmK<0, 3>(sh, attn_o, D, a.sa_out_w + (size_t)l * D * D, D,
                    nullptr, a.part + (size_t)(nk >> 3) * B * D, D,
                    MMAP(blk) * 64, (nk & 7) * 64, (nk >> 3) * 128, 128,
                    nullptr, nullptr, 0, nullptr, nullptr, nullptr, nullptr);
      }
      grid_bar(bno);

      // x = LN2( LN1(x + sum4(part) + bo) + ca_add[l] ) — 4 rows/block
      if (blk < 64) {
        const int row = blk * 4 + (threadIdx.x >> 7);
        const int cc = (threadIdx.x & 127) * 4;
        const size_t o = (size_t)row * D + cc;
        f4 u;
        if (l == 0) {           // recompute embedding (x never materialized)
          const float vv = a.vals[(size_t)t * B + row];
          u = vv * (*(const f4*)(a.ve_W + cc)) + *(const f4*)(a.ve_b + cc)
              + *(const f4*)(a.pe + (size_t)t * D + cc);
        } else {
          u = gld4e(a.x + o);
        }
        u += *(const f4*)(a.sa_out_b + l * D + cc);
        u += gld4e(a.part + o);
        u += gld4e(a.part + (size_t)B * D + o);
        u += gld4e(a.part + (size_t)2 * B * D + o);
        u += gld4e(a.part + (size_t)3 * B * D + o);
        const float m1 = rsum128(u.x + u.y + u.z + u.w, sbf) * (1.0f / D);
        f4 d = u - m1;
        const float v1 =
            rsum128(d.x * d.x + d.y * d.y + d.z * d.z + d.w * d.w, sbf)
            * (1.0f / D);
        f4 z = d * rsqrtf(v1 + 1e-5f) * (*(const f4*)(a.ln1_w + l * D + cc))
               + *(const f4*)(a.ln1_b + l * D + cc);
        f4 r2 = z + *(const f4*)(a.ca_add + (size_t)l * B * D + o);  // plain
        const float m2 = rsum128(r2.x + r2.y + r2.z + r2.w, sbf) * (1.0f / D);
        f4 d2 = r2 - m2;
        const float v2 =
            rsum128(d2.x * d2.x + d2.y * d2.y + d2.z * d2.z + d2.w * d2.w,
                    sbf) * (1.0f / D);
        f4 z2 = d2 * rsqrtf(v2 + 1e-5f) * (*(const f4*)(a.ln2_w + l * D + cc))
                + *(const f4*)(a.ln2_b + l * D + cc);
        gst4(a.x + o, z2);
      }
      grid_bar(bno);

      // FFN1: hbuf = gelu(x @ W1^T + b1)   (128 jobs, swizzled)
      if (blk < 128)
        gemmK<0, 1>(sh, a.x, D, a.lin1_w + (size_t)l * FF * D, D,
                    a.lin1_b + l * FF, a.hbuf, FF,
                    MMAP(blk) * 64, NKMAP(blk) * 64, 0, 512,
                    nullptr, nullptr, 0, nullptr, nullptr, nullptr, nullptr);
      grid_bar(bno);

      // FFN2 split-K8 (256 jobs, swizzled): part[kc] partials
      {
        const int nk = NKMAP(blk);
        gemmK<0, 3>(sh, a.hbuf, FF, a.lin2_w + (size_t)l * D * FF, FF,
                    nullptr, a.part + (size_t)(nk >> 3) * B * D, D,
                    MMAP(blk) * 64, (nk & 7) * 64, (nk >> 3) * 256, 256,
                    nullptr, nullptr, 0, nullptr, nullptr, nullptr, nullptr);
      }
      grid_bar(bno);

      // x = LN3( x + sum8(part) + b2 ) — 4 rows/block
      if (blk < 64) {
        const int row = blk * 4 + (threadIdx.x >> 7);
        const int cc = (threadIdx.x & 127) * 4;
        const size_t o = (size_t)row * D + cc;
        f4 s0 = gld4e(a.x + o) + *(const f4*)(a.lin2_b + l * D + cc);
#pragma unroll
        for (int kc = 0; kc < 8; kc++)
          s0 += gld4e(a.part + (size_t)kc * B * D + o);
        const float m1 = rsum128(s0.x + s0.y + s0.z + s0.w, sbf) * (1.0f / D);
        f4 d = s0 - m1;
        const float v1 =
            rsum128(d.x * d.x + d.y * d.y + d.z * d.z + d.w * d.w, sbf)
            * (1.0f / D);
        f4 z = d * rsqrtf(v1 + 1e-5f) * (*(const f4*)(a.ln3_w + l * D + cc))
               + *(const f4*)(a.ln3_b + l * D + cc);
        gst4(a.x + o, z);
      }
      grid_bar(bno);
    }

    // head stage 1: hh = gelu(x @ o1_w^T + o1_b)   (16 jobs)
    if (blk < 16)
      gemmK<0, 1>(sh, a.x, D, a.o1_w, D, a.o1_b, a.hh, 256,
                  (blk & 3) * 64, (blk >> 2) * 64, 0, 512,
                  nullptr, nullptr, 0, nullptr, nullptr, nullptr, nullptr);
    grid_bar(bno);

    // head stage 2: nv = hh @ o2_w^T + o2_b ; store out + vals[t+1]
    if (blk < 32) {
      const int wid = threadIdx.x >> 6, lane = threadIdx.x & 63;
      const int r = blk * 8 + wid;
      const f4 hv = gld4e(a.hh + (size_t)r * 256 + lane * 4);
      const f4 wv = *(const f4*)(a.o2_w + lane * 4);
      float pp = hv.x * wv.x + hv.y * wv.y + hv.z * wv.z + hv.w * wv.w;
#pragma unroll
      for (int o = 32; o; o >>= 1) pp += __shfl_xor(pp, o);
      if (lane == 0) {
        const float v = pp + a.o2_b[0];
        gst(a.vals + (size_t)(t + 1) * B + r, v);
        a.out[(size_t)r * P + t] = v;
      }
    }
    grid_bar(bno);
  }

  if (blk == 0 && threadIdx.x == 0)
    __hip_atomic_store(&g_base, bno, __ATOMIC_RELAXED,
                       __HIP_MEMORY_SCOPE_AGENT);
}

// ---------------------------------------------------------------------------
extern "C" void kernel_launch(void* const* d_in, const int* in_sizes, int n_in,
                              void* d_out, int out_size, void* d_ws,
                              size_t ws_size, hipStream_t stream)
{
  (void)in_sizes; (void)n_in; (void)out_size; (void)ws_size;
  MegaArgs h;
  h.context     = (const float*)d_in[0];
  h.start_token = (const float*)d_in[1];
  h.ctx_W  = (const float*)d_in[2];
  h.ctx_b  = (const float*)d_in[3];
  h.ve_W   = (const float*)d_in[4];
  h.ve_b   = (const float*)d_in[5];
  h.sa_in_w  = (const float*)d_in[6];
  h.sa_in_b  = (const float*)d_in[7];
  h.sa_out_w = (const float*)d_in[8];
  h.sa_out_b = (const float*)d_in[9];
  h.ca_in_w  = (const float*)d_in[10];
  h.ca_in_b  = (const float*)d_in[11];
  h.ca_out_w = (const float*)d_in[12];
  h.ca_out_b = (const float*)d_in[13];
  h.lin1_w = (const float*)d_in[14];
  h.lin1_b = (const float*)d_in[15];
  h.lin2_w = (const float*)d_in[16];
  h.lin2_b = (const float*)d_in[17];
  h.ln1_w = (const float*)d_in[18];
  h.ln1_b = (const float*)d_in[19];
  h.ln2_w = (const float*)d_in[20];
  h.ln2_b = (const float*)d_in[21];
  h.ln3_w = (const float*)d_in[22];
  h.ln3_b = (const float*)d_in[23];
  h.o1_w = (const float*)d_in[24];
  h.o1_b = (const float*)d_in[25];
  h.o2_w = (const float*)d_in[26];
  h.o2_b = (const float*)d_in[27];
  h.out = (float*)d_out;

  float* ws = (float*)d_ws;
  size_t off = 0;
  h.pe      = ws + off; off += (size_t)P * D;
  h.vals    = ws + off; off += (size_t)(P + 1) * B;
  h.memory  = ws + off; off += (size_t)B * D;
  h.ca_add  = ws + off; off += (size_t)L * B * D;
  h.x       = ws + off; off += (size_t)B * D;
  h.qbuf    = ws + off; off += (size_t)B * D;
  h.hbuf    = ws + off; off += (size_t)B * FF;
  h.part    = ws + off; off += (size_t)8 * B * D;  // part[4] = attn_o alias
  h.hh      = ws + off; off += (size_t)B * 256;
  h.kcache  = ws + off; off += (size_t)L * CS;
  h.vcache  = ws + off; off += (size_t)L * CS;

  void* kargs[] = { &h };
  hipLaunchCooperativeKernel(mega, dim3(NBLK), dim3(NTHR), kargs, 0, stream);
}

// Round 6
// 11075.456 us; speedup vs baseline: 1.1535x; 1.1535x over previous
//
#include <hip/hip_runtime.h>
#include <math.h>

// ---------------------------------------------------------------------------
// TimeSeriesTransformerDecoder — cooperative mega-kernel, v6.
//  * KV-cached incremental decoding (exact). Cross-attn T=1 -> const ca_add.
//  * v6 vs v5 (12.7ms, latency-chain bound, VALUBusy 10%):
//    - 32-deep k-chunks, double-buffered LDS, register prefetch via raw
//      GLD4 + vmcnt/sched_barrier fence -> staging latency hidden under FMA.
//    - fused per-row phases: attn+outproj+LN1+LN2 (block b = batch row b);
//      head1+head2 per-row (v5 ran head1 on 16 blocks, ~15us serial).
//    - QKV split-K2 (192 jobs), FFN2 split-K8 (256 jobs), LN3 per-row (256).
//      21 barriers/step vs 30 (507 total vs 723).
//    - barrier: 8 per-group generation lines + s_sleep backoff.
//    - KV cache written AND read only by block b -> XCD-L2 resident.
// ---------------------------------------------------------------------------

#define B    256
#define CTX  512
#define D    512
#define H    8
#define HD   64
#define L    4
#define FF   2048
#define P    24
#define NBLK 256
#define NTHR 512
#define NGRP 8
#define GSZ  32
#define CS   ((size_t)B * H * P * HD)

typedef float f4 __attribute__((ext_vector_type(4)));
typedef float f2 __attribute__((ext_vector_type(2)));

struct MegaArgs {
  const float *context, *start_token, *ctx_W, *ctx_b, *ve_W, *ve_b;
  const float *sa_in_w, *sa_in_b, *sa_out_w, *sa_out_b;
  const float *ca_in_w, *ca_in_b, *ca_out_w, *ca_out_b;
  const float *lin1_w, *lin1_b, *lin2_w, *lin2_b;
  const float *ln1_w, *ln1_b, *ln2_w, *ln2_b, *ln3_w, *ln3_b;
  const float *o1_w, *o1_b, *o2_w, *o2_b;
  float *out;
  float *pe, *vals, *ca_add, *x, *part, *hbuf, *kcache, *vcache;
};

// ---- coherent scalar access (relaxed agent atomics: sc0 sc1, no L2 flush)
__device__ __forceinline__ float gld(const float* p)
{
  return __hip_atomic_load((float*)p, __ATOMIC_RELAXED,
                           __HIP_MEMORY_SCOPE_AGENT);
}
__device__ __forceinline__ void gst(float* p, float v)
{
  __hip_atomic_store(p, v, __ATOMIC_RELAXED, __HIP_MEMORY_SCOPE_AGENT);
}
// ---- coherent vector ops (inline asm). GLD4/GLD1 issue WITHOUT wait;
//      gwait() = vmcnt(0) + sched_barrier so no consumer is hoisted into the
//      pending window (rule-18 discipline). gst4 = dwordx4 write-through.
#define GLD4(dst, ptr) \
  asm volatile("global_load_dwordx4 %0, %1, off sc0 sc1" \
               : "=&v"(dst) : "v"(ptr))
#define GLD1(dst, ptr) \
  asm volatile("global_load_dword %0, %1, off sc0 sc1" \
               : "=&v"(dst) : "v"(ptr))
__device__ __forceinline__ void gwait()
{
  asm volatile("s_waitcnt vmcnt(0)" ::: "memory");
  __builtin_amdgcn_sched_barrier(0);
}
__device__ __forceinline__ void gst4(float* p, f4 v)
{
  asm volatile("global_store_dwordx4 %0, %1, off sc0 sc1"
               :: "v"(p), "v"(v) : "memory");
}
__device__ __forceinline__ f4 gld4e(const float* p)   // load + embedded wait
{
  f4 r;
  GLD4(r, p);
  gwait();
  return r;
}

// ---- barrier state: monotonic across graph replays (no resets).
__device__ __align__(128) unsigned g_cnt[NGRP * 32];
__device__ __align__(128) unsigned g_root = 0;
__device__ __align__(128) unsigned g_gen[NGRP * 32];
__device__ __align__(128) unsigned g_base = 0;

__device__ __forceinline__ void grid_bar(unsigned &bno)
{
  ++bno;
  asm volatile("s_waitcnt vmcnt(0)" ::: "memory");  // drain asm sc1 stores
  __syncthreads();
  if (threadIdx.x == 0) {
    const int grp = blockIdx.x & (NGRP - 1);
    const unsigned o = __hip_atomic_fetch_add(&g_cnt[grp * 32], 1u,
                         __ATOMIC_RELAXED, __HIP_MEMORY_SCOPE_AGENT);
    if (o == bno * GSZ - 1u) {                  // last arriver of this group
      const unsigned r = __hip_atomic_fetch_add(&g_root, 1u,
                           __ATOMIC_RELAXED, __HIP_MEMORY_SCOPE_AGENT);
      if (r == bno * NGRP - 1u) {
#pragma unroll
        for (int g = 0; g < NGRP; g++)
          __hip_atomic_store(&g_gen[g * 32], bno, __ATOMIC_RELAXED,
                             __HIP_MEMORY_SCOPE_AGENT);
      }
    }
    if (__hip_atomic_load(&g_gen[grp * 32], __ATOMIC_RELAXED,
                          __HIP_MEMORY_SCOPE_AGENT) < bno) {
      do { __builtin_amdgcn_s_sleep(16); }
      while (__hip_atomic_load(&g_gen[grp * 32], __ATOMIC_RELAXED,
                               __HIP_MEMORY_SCOPE_AGENT) < bno);
    }
  }
  __syncthreads();
}

__device__ __forceinline__ float gelu_f(float v)
{
  return 0.5f * v * (1.0f + erff(v * 0.70710678118654752f));
}
__device__ __forceinline__ f4 gelu4(f4 v)
{
  v.x = gelu_f(v.x); v.y = gelu_f(v.y); v.z = gelu_f(v.z); v.w = gelu_f(v.w);
  return v;
}

// ---------------------------------------------------------------------------
// 64x64 tile GEMM over K chunk [k0,k0+KL). 512 thr, 2x4 micro-tile.
// 32-deep k-chunks, double-buffered LDS, register prefetch.
// LOADER: 0 = coherent (GLD4 sc1) A; 1 = embedding on the fly; 2 = plain A.
// EPI:    0 = +bias -> gst4 ; 1 = +bias+gelu -> gst4 ; 3 = raw -> gst4.
// ---------------------------------------------------------------------------
template <int LOADER, int EPI>
__device__ void gemmK(float* shmem,
                      const float* A, int lda,
                      const float* W, int ldw, const float* bias,
                      float* C, int ldc, int m0, int n0, int k0, int KL,
                      const float* valst, const float* veW, const float* veb,
                      const float* pet)
{
  const int tid = threadIdx.x;
  const int r  = tid >> 3;          // 0..63 staging row
  const int kl = (tid & 7) * 4;     // 0..28 staging k (f4)
  const int tm = tid >> 4;          // micro rows tm*2, tm*2+1
  const int tn = tid & 15;          // micro cols tn*4..+3

  float vsc = 0.f;
  if constexpr (LOADER == 1) vsc = valst[m0 + r];

  f4 va, vw;
  auto issue = [&](int kb) {
    const int k = k0 + kb + kl;
    if constexpr (LOADER == 1) {
      va = vsc * (*(const f4*)(veW + k)) + (*(const f4*)(veb + k))
           + (*(const f4*)(pet + k));
    } else if constexpr (LOADER == 2) {
      va = *(const f4*)(A + (size_t)(m0 + r) * lda + k);
    } else {
      GLD4(va, A + (size_t)(m0 + r) * lda + k);
    }
    vw = *(const f4*)(W + (size_t)(n0 + r) * ldw + k);
  };

  issue(0);
  float acc[2][4] = {};
  const int nch = KL / 32;
  for (int ch = 0; ch < nch; ch++) {
    float* as = shmem + (ch & 1) * (2 * 32 * 68);
    float* ws = as + 32 * 68;
    if constexpr (LOADER == 0) gwait();   // va ready; plain vw also drained
    as[(kl + 0) * 68 + r] = va.x;
    as[(kl + 1) * 68 + r] = va.y;
    as[(kl + 2) * 68 + r] = va.z;
    as[(kl + 3) * 68 + r] = va.w;
    ws[(kl + 0) * 68 + r] = vw.x;
    ws[(kl + 1) * 68 + r] = vw.y;
    ws[(kl + 2) * 68 + r] = vw.z;
    ws[(kl + 3) * 68 + r] = vw.w;
    __syncthreads();
    if (ch + 1 < nch) issue((ch + 1) * 32);   // prefetch overlaps compute
#pragma unroll
    for (int kk = 0; kk < 32; kk++) {
      const f2 a2 = *(const f2*)(as + kk * 68 + tm * 2);
      const f4 w4 = *(const f4*)(ws + kk * 68 + tn * 4);
      acc[0][0] = fmaf(a2.x, w4.x, acc[0][0]);
      acc[0][1] = fmaf(a2.x, w4.y, acc[0][1]);
      acc[0][2] = fmaf(a2.x, w4.z, acc[0][2]);
      acc[0][3] = fmaf(a2.x, w4.w, acc[0][3]);
      acc[1][0] = fmaf(a2.y, w4.x, acc[1][0]);
      acc[1][1] = fmaf(a2.y, w4.y, acc[1][1]);
      acc[1][2] = fmaf(a2.y, w4.z, acc[1][2]);
      acc[1][3] = fmaf(a2.y, w4.w, acc[1][3]);
    }
    __syncthreads();  // double buffer: one barrier per chunk is sufficient
  }

  const int n4 = n0 + tn * 4;
#pragma unroll
  for (int i = 0; i < 2; i++) {
    const int m = m0 + tm * 2 + i;
    f4 v = {acc[i][0], acc[i][1], acc[i][2], acc[i][3]};
    if constexpr (EPI != 3) v += *(const f4*)(bias + n4);
    if constexpr (EPI == 1) v = gelu4(v);
    gst4(C + (size_t)m * ldc + n4, v);
  }
}

// block-wide sum over 512 threads (8 waves)
__device__ __forceinline__ float rsum512(float v, float* sbf)
{
#pragma unroll
  for (int o = 32; o; o >>= 1) v += __shfl_xor(v, o);
  const int wid = threadIdx.x >> 6;
  if ((threadIdx.x & 63) == 0) sbf[wid] = v;
  __syncthreads();
  float s = 0.f;
#pragma unroll
  for (int w = 0; w < 8; w++) s += sbf[w];
  __syncthreads();
  return s;
}

__global__ __launch_bounds__(NTHR) void mega(MegaArgs a)
{
  __shared__ float sh[4 * 32 * 68];   // gemm staging (2 bufs x A,W)
  __shared__ float rowbuf[1536];      // fused-phase row state
  __shared__ float attn_s[512];
  __shared__ float sbf[8];
  const int blk = blockIdx.x;
  const int tid = threadIdx.x;
  unsigned bno = __hip_atomic_load(&g_base, __ATOMIC_RELAXED,
                                   __HIP_MEMORY_SCOPE_AGENT);

  float* qkvA = a.part;                       // alias: part[0..2]
  float* qkvB = a.part + (size_t)B * 1536;    // alias: part[3..5]
  float* memory = a.hbuf;                     // alias (setup only)

  // ---- S1: memory = context @ ctx_W^T + b | pe table | vals init
  if (blk < 32) {
    gemmK<2, 0>(sh, a.context, CTX, a.ctx_W, CTX, a.ctx_b, memory, D,
                (blk & 3) * 64, (blk >> 2) * 64, 0, 512,
                nullptr, nullptr, nullptr, nullptr);
  } else if (blk < 56) {
    const int tt = blk - 32;
    const float fr = expf((float)(tid & ~1) * (-9.210340371976184f / (float)D));
    const float ang = (float)tt * fr;
    gst(a.pe + tt * D + tid, (tid & 1) ? cosf(ang) : sinf(ang));
  } else if (blk == 56) {
    if (tid < B) gst(a.vals + tid, a.start_token[0]);
  }
  grid_bar(bno);

  // ---- S2: part[l] = memory @ Wv_ca[l]^T + bv   (T=1 cross-attn value)
  if (blk < 128) {
    const int l = blk >> 5, tile = blk & 31;
    gemmK<0, 0>(sh, memory, D,
                a.ca_in_w + (size_t)l * 3 * D * D + (size_t)2 * D * D, D,
                a.ca_in_b + l * 3 * D + 2 * D,
                a.part + (size_t)l * B * D, D,
                (tile & 3) * 64, (tile >> 2) * 64, 0, 512,
                nullptr, nullptr, nullptr, nullptr);
  }
  grid_bar(bno);

  // ---- S3: ca_add[l] = part[l] @ Wo_ca[l]^T + bo
  if (blk < 128) {
    const int l = blk >> 5, tile = blk & 31;
    gemmK<0, 0>(sh, a.part + (size_t)l * B * D, D,
                a.ca_out_w + (size_t)l * D * D, D, a.ca_out_b + l * D,
                a.ca_add + (size_t)l * B * D, D,
                (tile & 3) * 64, (tile >> 2) * 64, 0, 512,
                nullptr, nullptr, nullptr, nullptr);
  }
  grid_bar(bno);

  // ---- autoregressive decode --------------------------------------------
  for (int t = 0; t < P; t++) {
    for (int l = 0; l < L; l++) {
      float* kcp = a.kcache + (size_t)l * CS;
      float* vcp = a.vcache + (size_t)l * CS;

      // QKV split-K2: raw partials into qkvA/qkvB (192 jobs, XCD-affine:
      // blk = g*32 + m*8 + low3, wtile = g*8+low3 in 0..47)
      if (blk < 192) {
        const int wq = (blk >> 5) * 8 + (blk & 7);   // 0..47
        const int m = (blk >> 3) & 3;
        const int nt = wq >> 1, kc = wq & 1;
        float* dst = kc ? qkvB : qkvA;
        if (l == 0)
          gemmK<1, 3>(sh, nullptr, 0, a.sa_in_w, D, nullptr,
                      dst, 1536, m * 64, nt * 64, kc * 256, 256,
                      a.vals + (size_t)t * B, a.ve_W, a.ve_b,
                      a.pe + (size_t)t * D);
        else
          gemmK<0, 3>(sh, a.x, D, a.sa_in_w + (size_t)l * 3 * D * D, D,
                      nullptr, dst, 1536, m * 64, nt * 64, kc * 256, 256,
                      nullptr, nullptr, nullptr, nullptr);
      }
      grid_bar(bno);

      // ---- FUSED per-row phase: qkv-sum | KV finalize | attn | outproj |
      //      +residual | LN1 | +ca_add | LN2  (block b owns batch row b)
      {
        const int b = blk;
        // stage qkv = qA + qB + bias -> rowbuf[1536]
        if (tid < 384) {
          f4 pa, pb;
          GLD4(pa, qkvA + (size_t)b * 1536 + tid * 4);
          GLD4(pb, qkvB + (size_t)b * 1536 + tid * 4);
          gwait();
          f4 s = pa + pb + *(const f4*)(a.sa_in_b + l * 3 * D + tid * 4);
          *(f4*)(rowbuf + tid * 4) = s;
        }
        __syncthreads();
        // finalize KV cache row t (k: tid<128, v: tid<256)
        if (tid < 256) {
          const int half = tid >> 7;
          const int d = (tid & 127) * 4;
          const int h = d >> 6, hd = d & 63;
          f4 kv = *(const f4*)(rowbuf + 512 + half * 512 + d);
          float* cp = (half ? vcp : kcp)
                      + ((size_t)(b * H + h) * P + t) * HD + hd;
          gst4(cp, kv);
        }
        __syncthreads();   // drains gst4 -> row t readable below
        // attention: wave = head
        {
          const int h = tid >> 6, lane = tid & 63;
          const int g = lane >> 4, hd0 = (lane & 15) * 4;
          const float* kb = kcp + (size_t)(b * H + h) * P * HD;
          const float* vb = vcp + (size_t)(b * H + h) * P * HD;
          const f4 q4 = *(const f4*)(rowbuf + h * HD + hd0);
          const int nn = t + 1;
          float pp[6];
#pragma unroll
          for (int bt = 0; bt < 6; bt++) {
            const int j = bt * 4 + g;
            float s = -1e30f;
            if (j < nn) {
              const f4 k4 = *(const f4*)(kb + j * HD + hd0);
              s = q4.x * k4.x + q4.y * k4.y + q4.z * k4.z + q4.w * k4.w;
            }
#pragma unroll
            for (int o = 1; o <= 8; o <<= 1) s += __shfl_xor(s, o);
            pp[bt] = s * 0.125f;               // 1/sqrt(64)
          }
          float mx = -1e30f;
#pragma unroll
          for (int bt = 0; bt < 6; bt++)
            if (bt * 4 + g < nn) mx = fmaxf(mx, pp[bt]);
          mx = fmaxf(mx, __shfl_xor(mx, 16));
          mx = fmaxf(mx, __shfl_xor(mx, 32));
          float sum = 0.f;
#pragma unroll
          for (int bt = 0; bt < 6; bt++) {
            const int j = bt * 4 + g;
            const float e = (j < nn) ? expf(pp[bt] - mx) : 0.f;
            pp[bt] = e; sum += e;
          }
          sum += __shfl_xor(sum, 16);
          sum += __shfl_xor(sum, 32);
          const float inv = 1.0f / sum;
          f4 o4 = {0.f, 0.f, 0.f, 0.f};
#pragma unroll
          for (int j = 0; j < P; j++)
            if (j < nn) {
              const float pj = __shfl(pp[j >> 2], ((j & 3) << 4) | (lane & 15));
              const f4 v4 = *(const f4*)(vb + j * HD + hd0);
              o4 += pj * v4;
            }
          o4 *= inv;
          *(f4*)(attn_s + h * HD + hd0) = o4;
        }
        __syncthreads();
        // outproj (thread n owns element n) + residual + LN1 + ca + LN2
        {
          const int n = tid;
          const float* wrow = a.sa_out_w + (size_t)l * D * D + (size_t)n * D;
          float xres;
          if (l == 0) {
            const float vv = a.vals[(size_t)t * B + b];
            xres = vv * a.ve_W[n] + a.ve_b[n] + a.pe[(size_t)t * D + n];
          } else {
            xres = gld(a.x + (size_t)b * D + n);
          }
          float ac0 = 0.f, ac1 = 0.f, ac2 = 0.f, ac3 = 0.f;
#pragma unroll 4
          for (int k = 0; k < D; k += 16) {
            const f4 w0 = *(const f4*)(wrow + k);
            const f4 w1 = *(const f4*)(wrow + k + 4);
            const f4 w2 = *(const f4*)(wrow + k + 8);
            const f4 w3 = *(const f4*)(wrow + k + 12);
            const f4 x0 = *(const f4*)(attn_s + k);
            const f4 x1 = *(const f4*)(attn_s + k + 4);
            const f4 x2 = *(const f4*)(attn_s + k + 8);
            const f4 x3 = *(const f4*)(attn_s + k + 12);
            ac0 = fmaf(w0.x, x0.x, ac0); ac0 = fmaf(w0.y, x0.y, ac0);
            ac0 = fmaf(w0.z, x0.z, ac0); ac0 = fmaf(w0.w, x0.w, ac0);
            ac1 = fmaf(w1.x, x1.x, ac1); ac1 = fmaf(w1.y, x1.y, ac1);
            ac1 = fmaf(w1.z, x1.z, ac1); ac1 = fmaf(w1.w, x1.w, ac1);
            ac2 = fmaf(w2.x, x2.x, ac2); ac2 = fmaf(w2.y, x2.y, ac2);
            ac2 = fmaf(w2.z, x2.z, ac2); ac2 = fmaf(w2.w, x2.w, ac2);
            ac3 = fmaf(w3.x, x3.x, ac3); ac3 = fmaf(w3.y, x3.y, ac3);
            ac3 = fmaf(w3.z, x3.z, ac3); ac3 = fmaf(w3.w, x3.w, ac3);
          }
          float u = xres + (ac0 + ac1) + (ac2 + ac3) + a.sa_out_b[l * D + n];
          const float m1 = rsum512(u, sbf) * (1.0f / D);
          const float d1 = u - m1;
          const float v1 = rsum512(d1 * d1, sbf) * (1.0f / D);
          float z = d1 * rsqrtf(v1 + 1e-5f) * a.ln1_w[l * D + n]
                    + a.ln1_b[l * D + n];
          z += a.ca_add[(size_t)l * B * D + (size_t)b * D + n];   // plain
          const float m2 = rsum512(z, sbf) * (1.0f / D);
          const float d2 = z - m2;
          const float v2 = rsum512(d2 * d2, sbf) * (1.0f / D);
          rowbuf[n] = d2 * rsqrtf(v2 + 1e-5f) * a.ln2_w[l * D + n]
                      + a.ln2_b[l * D + n];
        }
        __syncthreads();
        if (tid < 128)
          gst4(a.x + (size_t)blk * D + tid * 4, *(const f4*)(rowbuf + tid * 4));
      }
      grid_bar(bno);

      // FFN1: hbuf = gelu(x @ W1^T + b1)   (128 jobs, XCD-affine)
      if (blk < 128) {
        const int wt = (blk >> 5) * 8 + (blk & 7);   // 0..31
        const int m = (blk >> 3) & 3;
        gemmK<0, 1>(sh, a.x, D, a.lin1_w + (size_t)l * FF * D, D,
                    a.lin1_b + l * FF, a.hbuf, FF,
                    m * 64, wt * 64, 0, 512,
                    nullptr, nullptr, nullptr, nullptr);
      }
      grid_bar(bno);

      // FFN2 split-K8: part[kc] raw partials   (256 jobs, XCD-affine)
      {
        const int wt = (blk >> 5) * 8 + (blk & 7);   // 0..63
        const int m = (blk >> 3) & 3;
        const int nt = wt >> 3, kc = wt & 7;
        gemmK<0, 3>(sh, a.hbuf, FF, a.lin2_w + (size_t)l * D * FF, FF,
                    nullptr, a.part + (size_t)kc * B * D, D,
                    m * 64, nt * 64, kc * 256, 256,
                    nullptr, nullptr, nullptr, nullptr);
      }
      grid_bar(bno);

      // LN3 per-row: x = LN3( x + sum8(part) + b2 )
      {
        const int b = blk, n = tid;
        const size_t o = (size_t)b * D + n;
        float xv, p0, p1, p2, p3, p4, p5, p6, p7;
        GLD1(xv, a.x + o);
        GLD1(p0, a.part + o);
        GLD1(p1, a.part + (size_t)1 * B * D + o);
        GLD1(p2, a.part + (size_t)2 * B * D + o);
        GLD1(p3, a.part + (size_t)3 * B * D + o);
        GLD1(p4, a.part + (size_t)4 * B * D + o);
        GLD1(p5, a.part + (size_t)5 * B * D + o);
        GLD1(p6, a.part + (size_t)6 * B * D + o);
        GLD1(p7, a.part + (size_t)7 * B * D + o);
        gwait();
        float s0 = xv + a.lin2_b[l * D + n]
                 + ((p0 + p1) + (p2 + p3)) + ((p4 + p5) + (p6 + p7));
        const float m1 = rsum512(s0, sbf) * (1.0f / D);
        const float d1 = s0 - m1;
        const float v1 = rsum512(d1 * d1, sbf) * (1.0f / D);
        rowbuf[n] = d1 * rsqrtf(v1 + 1e-5f) * a.ln3_w[l * D + n]
                    + a.ln3_b[l * D + n];
        __syncthreads();
        if (tid < 128)
          gst4(a.x + (size_t)b * D + tid * 4, *(const f4*)(rowbuf + tid * 4));
      }
      grid_bar(bno);
    }

    // ---- head fused per-row: out = gelu(x@o1^T+b1) @ o2^T + b2
    {
      const int b = blk;
      if (tid < 128)
        *(f4*)(rowbuf + tid * 4) = gld4e(a.x + (size_t)b * D + tid * 4);
      __syncthreads();
      if (tid < 256) {
        const float* wrow = a.o1_w + (size_t)tid * D;
        float ac0 = 0.f, ac1 = 0.f, ac2 = 0.f, ac3 = 0.f;
#pragma unroll 4
        for (int k = 0; k < D; k += 16) {
          const f4 w0 = *(const f4*)(wrow + k);
          const f4 w1 = *(const f4*)(wrow + k + 4);
          const f4 w2 = *(const f4*)(wrow + k + 8);
          const f4 w3 = *(const f4*)(wrow + k + 12);
          const f4 x0 = *(const f4*)(rowbuf + k);
          const f4 x1 = *(const f4*)(rowbuf + k + 4);
          const f4 x2 = *(const f4*)(rowbuf + k + 8);
          const f4 x3 = *(const f4*)(rowbuf + k + 12);
          ac0 = fmaf(w0.x, x0.x, ac0); ac0 = fmaf(w0.y, x0.y, ac0);
          ac0 = fmaf(w0.z, x0.z, ac0); ac0 = fmaf(w0.w, x0.w, ac0);
          ac1 = fmaf(w1.x, x1.x, ac1); ac1 = fmaf(w1.y, x1.y, ac1);
          ac1 = fmaf(w1.z, x1.z, ac1); ac1 = fmaf(w1.w, x1.w, ac1);
          ac2 = fmaf(w2.x, x2.x, ac2); ac2 = fmaf(w2.y, x2.y, ac2);
          ac2 = fmaf(w2.z, x2.z, ac2); ac2 = fmaf(w2.w, x2.w, ac2);
          ac3 = fmaf(w3.x, x3.x, ac3); ac3 = fmaf(w3.y, x3.y, ac3);
          ac3 = fmaf(w3.z, x3.z, ac3); ac3 = fmaf(w3.w, x3.w, ac3);
        }
        attn_s[tid] = gelu_f((ac0 + ac1) + (ac2 + ac3) + a.o1_b[tid]);
      }
      __syncthreads();
      if (tid < 64) {
        float p = 0.f;
#pragma unroll
        for (int j = 0; j < 4; j++)
          p = fmaf(attn_s[tid * 4 + j], a.o2_w[tid * 4 + j], p);
#pragma unroll
        for (int o = 32; o; o >>= 1) p += __shfl_xor(p, o);
        if (tid == 0) {
          const float v = p + a.o2_b[0];
          gst(a.vals + (size_t)(t + 1) * B + b, v);
          a.out[(size_t)b * P + t] = v;
        }
      }
    }
    grid_bar(bno);
  }

  if (blk == 0 && tid == 0)
    __hip_atomic_store(&g_base, bno, __ATOMIC_RELAXED,
                       __HIP_MEMORY_SCOPE_AGENT);
}

// ---------------------------------------------------------------------------
extern "C" void kernel_launch(void* const* d_in, const int* in_sizes, int n_in,
                              void* d_out, int out_size, void* d_ws,
                              size_t ws_size, hipStream_t stream)
{
  (void)in_sizes; (void)n_in; (void)out_size; (void)ws_size;
  MegaArgs h;
  h.context     = (const float*)d_in[0];
  h.start_token = (const float*)d_in[1];
  h.ctx_W  = (const float*)d_in[2];
  h.ctx_b  = (const float*)d_in[3];
  h.ve_W   = (const float*)d_in[4];
  h.ve_b   = (const float*)d_in[5];
  h.sa_in_w  = (const float*)d_in[6];
  h.sa_in_b  = (const float*)d_in[7];
  h.sa_out_w = (const float*)d_in[8];
  h.sa_out_b = (const float*)d_in[9];
  h.ca_in_w  = (const float*)d_in[10];
  h.ca_in_b  = (const float*)d_in[11];
  h.ca_out_w = (const float*)d_in[12];
  h.ca_out_b = (const float*)d_in[13];
  h.lin1_w = (const float*)d_in[14];
  h.lin1_b = (const float*)d_in[15];
  h.lin2_w = (const float*)d_in[16];
  h.lin2_b = (const float*)d_in[17];
  h.ln1_w = (const float*)d_in[18];
  h.ln1_b = (const float*)d_in[19];
  h.ln2_w = (const float*)d_in[20];
  h.ln2_b = (const float*)d_in[21];
  h.ln3_w = (const float*)d_in[22];
  h.ln3_b = (const float*)d_in[23];
  h.o1_w = (const float*)d_in[24];
  h.o1_b = (const float*)d_in[25];
  h.o2_w = (const float*)d_in[26];
  h.o2_b = (const float*)d_in[27];
  h.out = (float*)d_out;

  float* ws = (float*)d_ws;
  size_t off = 0;
  h.pe      = ws + off; off += (size_t)P * D;          // 12288
  h.vals    = ws + off; off += (size_t)(P + 1) * B;    // 6400
  h.ca_add  = ws + off; off += (size_t)L * B * D;      // 524288
  h.x       = ws + off; off += (size_t)B * D;          // 131072
  h.part    = ws + off; off += (size_t)8 * B * D;      // 1048576 (qkvA/B alias)
  h.hbuf    = ws + off; off += (size_t)B * FF;         // 524288 (memory alias)
  h.kcache  = ws + off; off += (size_t)L * CS;         // 12582912
  h.vcache  = ws + off; off += (size_t)L * CS;         // 12582912
  // total 27,412,736 floats = 109.7 MB (< v5's proven 111 MB)

  void* kargs[] = { &h };
  hipLaunchCooperativeKernel(mega, dim3(NBLK), dim3(NTHR), kargs, 0, stream);
}